// Round 14
// baseline (166.388 us; speedup 1.0000x reference)
//
#include <hip/hip_runtime.h>
#include <stdint.h>

// Problem constants
#define T_ 4
#define B_ 16
#define N_ 197
#define D_ 512
#define H_ 8
#define DH 64
#define BN_ (B_*N_)              // 3152 rows per timestep
#define PLANE (BN_*D_)           // 1,613,824 elems per t-plane
#define M_ (T_*BN_)              // 12608 GEMM rows
#define TENSOR_ELEMS (T_*PLANE)  // 6,455,296 elems per (T,B,N,D) tensor
#define WELEMS (D_*D_)           // 262,144
#define MH (M_*H_)               // 100,864 bitmask words per tensor
#define FLAG_TOL 6e-3f           // ~13 sigma of single-pass f16 dot error
#define NFW3 (3*PLANE/64)        // 75,648 flag words (qkv)
#define NFWP (PLANE/64)          // 25,216 flag words (proj / per plane)

typedef __attribute__((ext_vector_type(8))) short short8v;
typedef __attribute__((ext_vector_type(8))) _Float16 f16x8;
typedef __attribute__((ext_vector_type(4))) float f32x4;
typedef __attribute__((ext_vector_type(4))) unsigned short ushort4v;
typedef unsigned long long u64;
typedef unsigned int u32;

__device__ __forceinline__ ushort f16_bits(float f) {
    _Float16 h = (_Float16)f;                      // v_cvt_f16_f32, RNE
    return __builtin_bit_cast(unsigned short, h);
}
__device__ __forceinline__ float f16_val(ushort u) {
    return (float)__builtin_bit_cast(_Float16, u);
}

// async global->LDS 16B copy (one per lane; dest = wave base + lane*16)
__device__ __forceinline__ void gload16(const void* g, void* l) {
    __builtin_amdgcn_global_load_lds(
        (const __attribute__((address_space(1))) unsigned int*)g,
        (__attribute__((address_space(3))) unsigned int*)l, 16, 0, 0);
}

// 8 spike bits -> bf16 0/1 fragment
__device__ __forceinline__ short8v unpack8(u32 bits) {
    short8v r;
    #pragma unroll
    for (int j = 0; j < 8; ++j)
        r[j] = (short)(((bits >> j) & 1u) ? 0x3F80 : 0);
    return r;
}

// ---------------------------------------------------------------------------
// Batched f32 -> f16 convert (x + Wq + Wk + Wv + Wp in one launch)
// ---------------------------------------------------------------------------
#define NBX (TENSOR_ELEMS/1024)  // 6304
#define NBW (WELEMS/1024)        // 256

__global__ void cvt_all(const float* __restrict__ x,  const float* __restrict__ Wq,
                        const float* __restrict__ Wk, const float* __restrict__ Wv,
                        const float* __restrict__ Wp,
                        ushort* __restrict__ xh, ushort* __restrict__ w3h,
                        ushort* __restrict__ wph)
{
    int b = blockIdx.x;
    const float* src; ushort* dst; int base;
    if      (b < NBX)         { src = x;  dst = xh;             base = b; }
    else if (b < NBX + NBW)   { src = Wq; dst = w3h;            base = b - NBX; }
    else if (b < NBX + 2*NBW) { src = Wk; dst = w3h + WELEMS;   base = b - NBX - NBW; }
    else if (b < NBX + 3*NBW) { src = Wv; dst = w3h + 2*WELEMS; base = b - NBX - 2*NBW; }
    else                      { src = Wp; dst = wph;            base = b - NBX - 3*NBW; }
    int i = (base*256 + threadIdx.x)*4;
    float4 v = *(const float4*)(src + i);
    ushort4v o;
    o[0] = f16_bits(v.x); o[1] = f16_bits(v.y);
    o[2] = f16_bits(v.z); o[3] = f16_bits(v.w);
    *(ushort4v*)(dst + i) = o;
}

// ---------------------------------------------------------------------------
// Fused f16 GEMM + LIF + spike-bit pack (QKV). m97-style micro-tile:
// mfma_f32_16x16x32_f16, 2x2 wave grid, wave = 64x64 output, acc[4][4] f32x4,
// 8 ds_read_b128 : 16 MFMA per wave per K-step. A-tile LDS rows permuted
// lrow = row32*4 + t, so each C-fragment's 4 regs = the 4 timesteps of one
// (row,col): LIF chain lives in the accumulator registers; epilogue is pure
// ballot + 16-bit-slice word assembly (no LDS, no atomics).
// Tile: 32 row32 x 4 t (=128 rows) x 128 cols. BK=32, dbuf 32 KB.
// ---------------------------------------------------------------------------
__global__ __launch_bounds__(256, 3)
void gemm_qkv_lif(const ushort* __restrict__ xh, const ushort* __restrict__ w3h,
                  u64* __restrict__ bits3, u64* __restrict__ fmap3)
{
    __shared__ __align__(16) ushort smem[16384];   // dbuf x (A 8KB | B 8KB)
    const int tid = threadIdx.x;
    const int lane = tid & 63, wid = tid >> 6;
    const int wm = wid >> 1, wn = wid & 1;
    const int il = lane & 15, g = lane >> 4;
    const int nyz = 12, nz = 3;

    // bijective XCD swizzle + yz-fastest decode
    int nwg = gridDim.x, orig = blockIdx.x;
    int q8 = nwg >> 3, r8 = nwg & 7, xcd = orig & 7, loc = orig >> 3;
    int wg = (xcd < r8 ? xcd*(q8+1) : r8*(q8+1) + (xcd-r8)*q8) + loc;
    int bx = wg / nyz, yz = wg - bx*nyz;
    int by = yz / nz,  z  = yz - by*nz;

    const int bm0 = bx * 32;                       // row32 offset within BN_
    const int bn0 = by * 128;
    const ushort* Wz = w3h + (size_t)z * WELEMS;

    f32x4 acc[4][4];
    #pragma unroll
    for (int i = 0; i < 4; ++i)
        #pragma unroll
        for (int j = 0; j < 4; ++j)
            acc[i][j] = (f32x4){0.f, 0.f, 0.f, 0.f};

    auto STAGE = [&](int buf, int kt) {
        #pragma unroll
        for (int i = 0; i < 4; ++i) {
            const int q = ((i & 1) << 8) | tid;    // chunk id [0,512)
            const int c = q >> 7, lrow = q & 127;  // LDS [c][lrow][8]
            ushort* dst = smem + buf*8192 + ((i >> 1) << 12) + q*8;
            if (i < 2) {                           // A: lrow = row32*4 + t
                int row32 = lrow >> 2, t = lrow & 3;
                int gr = bm0 + row32; if (gr > BN_-1) gr = BN_-1;
                gload16(xh + ((size_t)(t*BN_ + gr)*D_ + kt + c*8), dst);
            } else {                               // B: lrow = col
                gload16(Wz + ((size_t)(bn0 + lrow)*D_ + kt + c*8), dst);
            }
        }
    };
    auto COMPUTE = [&](int buf) {
        const ushort* Ab = smem + buf*8192;
        const ushort* Bb = Ab + 4096;
        f16x8 a[4], b[4];
        #pragma unroll
        for (int i = 0; i < 4; ++i)
            a[i] = *(const f16x8*)&Ab[(g*128 + wm*64 + i*16 + il)*8];
        #pragma unroll
        for (int j = 0; j < 4; ++j)
            b[j] = *(const f16x8*)&Bb[(g*128 + wn*64 + j*16 + il)*8];
        #pragma unroll
        for (int i = 0; i < 4; ++i)
            #pragma unroll
            for (int j = 0; j < 4; ++j)
                acc[i][j] = __builtin_amdgcn_mfma_f32_16x16x32_f16(a[i], b[j], acc[i][j], 0, 0, 0);
    };

    STAGE(0, 0);
    __syncthreads();
    int cur = 0;
    #pragma unroll
    for (int k32 = 0; k32 < 16; ++k32) {
        if (k32 < 15) STAGE(cur ^ 1, (k32 + 1)*32);
        COMPUTE(cur);
        __syncthreads();
        cur ^= 1;
    }

    // ---- fused LIF epilogue (registers only) ----
    // acc[i][j][t]: row32 = bm0 + wm*16 + i*4 + g, col = bn0 + wn*64 + j*16 + il
    #pragma unroll
    for (int i = 0; i < 4; ++i) {
        bool s[4][4]; bool fg[4];
        #pragma unroll
        for (int j = 0; j < 4; ++j) {
            fg[j] = false; float v = 0.f;
            #pragma unroll
            for (int t = 0; t < 4; ++t) {
                float h = v + (acc[i][j][t] - v)*0.5f;
                s[j][t] = h >= 1.0f;
                fg[j] |= fabsf(h - 1.0f) < FLAG_TOL;
                v = s[j][t] ? 0.f : h;
            }
        }
        #pragma unroll
        for (int t = 0; t < 4; ++t) {
            u64 b0 = __ballot(s[0][t]), b1 = __ballot(s[1][t]);
            u64 b2 = __ballot(s[2][t]), b3 = __ballot(s[3][t]);
            if (lane < 4) {
                int sh = lane*16;
                u64 w = ((b0 >> sh) & 0xFFFFull)
                      | (((b1 >> sh) & 0xFFFFull) << 16)
                      | (((b2 >> sh) & 0xFFFFull) << 32)
                      | (((b3 >> sh) & 0xFFFFull) << 48);
                int row32 = bm0 + wm*16 + i*4 + lane;
                if (row32 < BN_)
                    bits3[(size_t)z*MH + (size_t)(t*BN_ + row32)*H_ + by*2 + wn] = w;
            }
        }
        u64 f0 = __ballot(fg[0]), f1 = __ballot(fg[1]);
        u64 f2 = __ballot(fg[2]), f3 = __ballot(fg[3]);
        if (lane < 4) {
            int sh = lane*16;
            u64 w = ((f0 >> sh) & 0xFFFFull)
                  | (((f1 >> sh) & 0xFFFFull) << 16)
                  | (((f2 >> sh) & 0xFFFFull) << 32)
                  | (((f3 >> sh) & 0xFFFFull) << 48);
            int row32 = bm0 + wm*16 + i*4 + lane;
            if (row32 < BN_)
                fmap3[(size_t)z*NFWP + (size_t)row32*8 + by*2 + wn] = w;
        }
    }
}

// ---------------------------------------------------------------------------
// Fused f16 GEMM + bias + LIF (proj). Same micro-tile; writes out_spk f32 0/1
// + flag bitmap directly from accumulator t-chains.
// ---------------------------------------------------------------------------
__global__ __launch_bounds__(256, 3)
void gemm_proj_lif(const ushort* __restrict__ oh, const ushort* __restrict__ wph,
                   const float* __restrict__ bias, float* __restrict__ outp,
                   u64* __restrict__ fmapp)
{
    __shared__ __align__(16) ushort smem[16384];
    const int tid = threadIdx.x;
    const int lane = tid & 63, wid = tid >> 6;
    const int wm = wid >> 1, wn = wid & 1;
    const int il = lane & 15, g = lane >> 4;
    const int nyz = 4;

    int nwg = gridDim.x, orig = blockIdx.x;
    int q8 = nwg >> 3, r8 = nwg & 7, xcd = orig & 7, loc = orig >> 3;
    int wg = (xcd < r8 ? xcd*(q8+1) : r8*(q8+1) + (xcd-r8)*q8) + loc;
    int bx = wg / nyz, by = wg - bx*nyz;

    const int bm0 = bx * 32, bn0 = by * 128;

    f32x4 acc[4][4];
    #pragma unroll
    for (int i = 0; i < 4; ++i)
        #pragma unroll
        for (int j = 0; j < 4; ++j)
            acc[i][j] = (f32x4){0.f, 0.f, 0.f, 0.f};

    auto STAGE = [&](int buf, int kt) {
        #pragma unroll
        for (int i = 0; i < 4; ++i) {
            const int q = ((i & 1) << 8) | tid;
            const int c = q >> 7, lrow = q & 127;
            ushort* dst = smem + buf*8192 + ((i >> 1) << 12) + q*8;
            if (i < 2) {
                int row32 = lrow >> 2, t = lrow & 3;
                int gr = bm0 + row32; if (gr > BN_-1) gr = BN_-1;
                gload16(oh + ((size_t)(t*BN_ + gr)*D_ + kt + c*8), dst);
            } else {
                gload16(wph + ((size_t)(bn0 + lrow)*D_ + kt + c*8), dst);
            }
        }
    };
    auto COMPUTE = [&](int buf) {
        const ushort* Ab = smem + buf*8192;
        const ushort* Bb = Ab + 4096;
        f16x8 a[4], b[4];
        #pragma unroll
        for (int i = 0; i < 4; ++i)
            a[i] = *(const f16x8*)&Ab[(g*128 + wm*64 + i*16 + il)*8];
        #pragma unroll
        for (int j = 0; j < 4; ++j)
            b[j] = *(const f16x8*)&Bb[(g*128 + wn*64 + j*16 + il)*8];
        #pragma unroll
        for (int i = 0; i < 4; ++i)
            #pragma unroll
            for (int j = 0; j < 4; ++j)
                acc[i][j] = __builtin_amdgcn_mfma_f32_16x16x32_f16(a[i], b[j], acc[i][j], 0, 0, 0);
    };

    STAGE(0, 0);
    __syncthreads();
    int cur = 0;
    #pragma unroll
    for (int k32 = 0; k32 < 16; ++k32) {
        if (k32 < 15) STAGE(cur ^ 1, (k32 + 1)*32);
        COMPUTE(cur);
        __syncthreads();
        cur ^= 1;
    }

    const int colbase = bn0 + wn*64;
    float bb[4];
    #pragma unroll
    for (int j = 0; j < 4; ++j) bb[j] = bias[colbase + j*16 + il];

    #pragma unroll
    for (int i = 0; i < 4; ++i) {
        const int myrow = bm0 + wm*16 + i*4 + g;
        const bool live = myrow < BN_;
        bool fg[4];
        #pragma unroll
        for (int j = 0; j < 4; ++j) {
            fg[j] = false; float v = 0.f;
            #pragma unroll
            for (int t = 0; t < 4; ++t) {
                float h = v + ((acc[i][j][t] + bb[j]) - v)*0.5f;
                bool st = h >= 1.0f;
                fg[j] |= fabsf(h - 1.0f) < FLAG_TOL;
                if (live)
                    outp[(size_t)t*PLANE + (size_t)myrow*D_ + colbase + j*16 + il] =
                        st ? 1.0f : 0.0f;
                v = st ? 0.f : h;
            }
        }
        u64 f0 = __ballot(fg[0]), f1 = __ballot(fg[1]);
        u64 f2 = __ballot(fg[2]), f3 = __ballot(fg[3]);
        if (lane < 4) {
            int sh = lane*16;
            u64 w = ((f0 >> sh) & 0xFFFFull)
                  | (((f1 >> sh) & 0xFFFFull) << 16)
                  | (((f2 >> sh) & 0xFFFFull) << 32)
                  | (((f3 >> sh) & 0xFFFFull) << 48);
            int row32 = bm0 + wm*16 + i*4 + lane;
            if (row32 < BN_)
                fmapp[(size_t)row32*8 + by*2 + wn] = w;
        }
    }
}

// ---------------------------------------------------------------------------
// f64 exact recompute of flagged chains (bitmap scan, 4 waves/block, ILP).
// ---------------------------------------------------------------------------
__global__ __launch_bounds__(256)
void fixup_qkv(const float* __restrict__ x,
               const float* __restrict__ Wq, const float* __restrict__ Wk,
               const float* __restrict__ Wv,
               u64* __restrict__ bits3, const u64* __restrict__ flagmap)
{
    const int lane = threadIdx.x & 63;
    const int wv = blockIdx.x*4 + (threadIdx.x >> 6);
    const int nw = gridDim.x*4;
    for (int w = wv; w < NFW3; w += nw) {
        u64 fm = flagmap[w];
        while (fm) {
            int bit = __ffsll((long long)fm) - 1;
            fm &= fm - 1;
            int id = (w << 6) + bit;
            int tsr = id / PLANE;
            int rem = id - tsr*PLANE;
            int r = rem >> 9, e = rem & (D_-1);
            const float* W = (tsr==0) ? Wq : (tsr==1 ? Wk : Wv);
            const float* wr = W + (size_t)e*D_;
            u64* bits = bits3 + (size_t)tsr*MH;
            float wv8[8];
            #pragma unroll
            for (int i = 0; i < 8; ++i) wv8[i] = wr[lane + 64*i];
            double dots[T_];
            #pragma unroll
            for (int t = 0; t < T_; ++t) {
                const float* xr = x + (size_t)(t*BN_ + r)*D_;
                float xv8[8];
                #pragma unroll
                for (int i = 0; i < 8; ++i) xv8[i] = xr[lane + 64*i];
                double p = 0.0;
                #pragma unroll
                for (int i = 0; i < 8; ++i) p += (double)xv8[i]*(double)wv8[i];
                dots[t] = p;
            }
            #pragma unroll
            for (int off = 32; off > 0; off >>= 1)
                #pragma unroll
                for (int t = 0; t < T_; ++t)
                    dots[t] += __shfl_down(dots[t], off);
            if (lane == 0) {
                double v = 0.0;
                u64 b = 1ull << (e & 63);
                #pragma unroll
                for (int t = 0; t < T_; ++t) {
                    double hh = v + (dots[t] - v)/2.0;
                    bool s = hh >= 1.0;
                    size_t wd = (size_t)(t*BN_ + r)*H_ + (e >> 6);
                    if (s) atomicOr(&bits[wd], b);
                    else   atomicAnd(&bits[wd], ~b);
                    v = s ? 0.0 : hh;
                }
            }
        }
    }
}

// ---------------------------------------------------------------------------
// Fused MFMA attention, z-split x2. Q/K fragments unpacked from spike
// bit-words; QK^T -> bf16 S strip in per-wave LDS (exact); attn_map coalesced
// row stores; PV against Vt -> of16.
// ---------------------------------------------------------------------------
#define JP 224   // 7 * 32 (padded j for PV K-dim)
#define VSTR 232 // LDS row stride for Vt / Ss

__global__ __launch_bounds__(256)
void attn_fused(const u64* __restrict__ qbits, const u64* __restrict__ kbits,
                const u64* __restrict__ vbits,
                float* __restrict__ attn_out, ushort* __restrict__ of16)
{
    __shared__ ushort Vt[DH][VSTR];
    __shared__ ushort Ss[4][16][VSTR];
    int tb = blockIdx.x, h = blockIdx.y, zh = blockIdx.z;
    int tid = threadIdx.x, wave = tid >> 6, lane = tid & 63;

    // stage V transposed from vbits: Vt[d][j], j >= N_ zeroed
    for (int idx = tid; idx < JP*16; idx += 256) {
        int j = idx >> 4, d4 = (idx & 15) << 2;
        ushort vv[4] = {0,0,0,0};
        if (j < N_) {
            u64 vw = vbits[((size_t)tb*N_ + j)*H_ + h];
            #pragma unroll
            for (int r = 0; r < 4; ++r)
                vv[r] = ((vw >> (d4+r)) & 1ull) ? 0x3F80 : 0;
        }
        Vt[d4+0][j]=vv[0]; Vt[d4+1][j]=vv[1]; Vt[d4+2][j]=vv[2]; Vt[d4+3][j]=vv[3];
    }
    // zero Ss pad cols [208, 224)
    for (int idx = lane; idx < 16*16; idx += 64)
        Ss[wave][idx >> 4][208 + (idx & 15)] = 0;
    __syncthreads();

    const int il = lane & 15, kk = (lane >> 4) << 3, ig = (lane >> 4) << 2;
    const size_t amap = ((size_t)tb*H_ + h)*(size_t)(N_*N_);

    const int it_lo = zh*7 + wave;                 // z=0: strips 0..6, z=1: 7..12
    const int it_hi = (zh*7 + 7 < 13) ? zh*7 + 7 : 13;
    for (int it = it_lo; it < it_hi; it += 4) {
        int i0 = it << 4;
        int qrow = i0 + il;
        u64 qw = (qrow < N_) ? qbits[((size_t)tb*N_ + qrow)*H_ + h] : 0ull;
        short8v a0 = unpack8((u32)(qw >> kk));
        short8v a1 = unpack8((u32)((qw >> 32) >> kk));
        for (int jt = 0; jt < 13; ++jt) {
            int j0 = jt << 4, jrow = j0 + il;
            u64 kw = (jrow < N_) ? kbits[((size_t)tb*N_ + jrow)*H_ + h] : 0ull;
            short8v b0 = unpack8((u32)(kw >> kk));
            short8v b1 = unpack8((u32)((kw >> 32) >> kk));
            f32x4 c = {0.f, 0.f, 0.f, 0.f};
            c = __builtin_amdgcn_mfma_f32_16x16x32_bf16(a0, b0, c, 0, 0, 0);
            c = __builtin_amdgcn_mfma_f32_16x16x32_bf16(a1, b1, c, 0, 0, 0);
            int j = j0 + il;               // C col = lane&15
            #pragma unroll
            for (int r = 0; r < 4; ++r) {
                float sv = c[r]*0.125f;    // exact: k/8, k <= 64
                Ss[wave][ig + r][j] = (ushort)(__float_as_uint(sv) >> 16);
            }
        }
        // coalesced attn_map row stores (bf16 -> f32 shift, exact)
        #pragma unroll
        for (int r = 0; r < 16; ++r) {
            int i = i0 + r;
            if (i < N_) {
                #pragma unroll
                for (int gg = 0; gg < 4; ++gg) {
                    int col = gg*64 + lane;
                    if (col < N_)
                        attn_out[amap + (size_t)i*N_ + col] =
                            __uint_as_float((u32)Ss[wave][r][col] << 16);
                }
            }
        }
        // PV for this strip
        f32x4 o[4];
        #pragma unroll
        for (int dt = 0; dt < 4; ++dt) o[dt] = (f32x4){0.f,0.f,0.f,0.f};
        #pragma unroll
        for (int kt = 0; kt < 7; ++kt) {
            short8v a = *(const short8v*)&Ss[wave][il][kt*32 + kk];
            #pragma unroll
            for (int dt = 0; dt < 4; ++dt) {
                short8v b = *(const short8v*)&Vt[dt*16 + il][kt*32 + kk];
                o[dt] = __builtin_amdgcn_mfma_f32_16x16x32_bf16(a, b, o[dt], 0, 0, 0);
            }
        }
        #pragma unroll
        for (int dt = 0; dt < 4; ++dt)
            #pragma unroll
            for (int r = 0; r < 4; ++r) {
                int i = i0 + ig + r;
                if (i < N_)
                    of16[((size_t)tb*N_ + i)*D_ + (size_t)h*DH + dt*16 + il] =
                        f16_bits(o[dt][r]);
            }
    }
}

// ---------------------------------------------------------------------------
// fixup_proj: exact f64 recompute of flagged proj chains (reads of16, exact).
// ---------------------------------------------------------------------------
__global__ __launch_bounds__(256)
void fixup_proj(const ushort* __restrict__ of16, const float* __restrict__ Wp,
                const float* __restrict__ bp, float* __restrict__ outp,
                const u64* __restrict__ flagmap)
{
    const int lane = threadIdx.x & 63;
    const int wv = blockIdx.x*4 + (threadIdx.x >> 6);
    const int nw = gridDim.x*4;
    for (int w = wv; w < NFWP; w += nw) {
        u64 fm = flagmap[w];
        while (fm) {
            int bit = __ffsll((long long)fm) - 1;
            fm &= fm - 1;
            int rem = (w << 6) + bit;
            int r = rem >> 9, e = rem & (D_-1);
            const float* wr = Wp + (size_t)e*D_;
            float wv8[8];
            #pragma unroll
            for (int i = 0; i < 8; ++i) wv8[i] = wr[lane + 64*i];
            double dots[T_];
            #pragma unroll
            for (int t = 0; t < T_; ++t) {
                const ushort* ar = of16 + (size_t)(t*BN_ + r)*D_;
                float av8[8];
                #pragma unroll
                for (int i = 0; i < 8; ++i) av8[i] = f16_val(ar[lane + 64*i]);
                double p = 0.0;
                #pragma unroll
                for (int i = 0; i < 8; ++i) p += (double)av8[i]*(double)wv8[i];
                dots[t] = p;
            }
            #pragma unroll
            for (int off = 32; off > 0; off >>= 1)
                #pragma unroll
                for (int t = 0; t < T_; ++t)
                    dots[t] += __shfl_down(dots[t], off);
            if (lane == 0) {
                double v = 0.0;
                #pragma unroll
                for (int t = 0; t < T_; ++t) {
                    double xt = dots[t] + (double)bp[e];
                    double h = v + (xt - v)/2.0;
                    bool s = h >= 1.0;
                    outp[(size_t)t*PLANE + rem] = s ? 1.0f : 0.0f;
                    v = s ? 0.0 : h;
                }
            }
        }
    }
}

// ---------------------------------------------------------------------------
extern "C" void kernel_launch(void* const* d_in, const int* in_sizes, int n_in,
                              void* d_out, int out_size, void* d_ws, size_t ws_size,
                              hipStream_t stream)
{
    const float* x  = (const float*)d_in[0];
    const float* Wq = (const float*)d_in[1];
    const float* Wk = (const float*)d_in[2];
    const float* Wv = (const float*)d_in[3];
    const float* Wp = (const float*)d_in[4];
    const float* bp = (const float*)d_in[5];
    float* out_spk  = (float*)d_out;                       // (T,B,N,D) spikes
    float* attn_out = (float*)d_out + TENSOR_ELEMS;        // (T,B,H,N,N)

    char* ws = (char*)d_ws;
    const size_t BUFB = (size_t)TENSOR_ELEMS * sizeof(float);   // 25.8 MB
    if (ws_size < 4*BUFB) return;
    // R2: O f16 (proj GEMM + fixup operand; exact)
    ushort* of16 = (ushort*)(ws + 2*BUFB);
    // R3: xh f16 | w3h | wph | bits | flag bitmaps
    char* r3 = ws + 3*BUFB;
    ushort* xh   = (ushort*)r3;                            // 12.9 MB
    ushort* w3h  = (ushort*)(r3 + (13u<<20));              // 1.5 MB
    ushort* wph  = (ushort*)(r3 + (15u<<20));              // 0.5 MB
    u64*    bits3 = (u64*)(r3 + (16u<<20));                // 2.42 MB
    u64*    qbits = bits3;
    u64*    kbits = bits3 + MH;
    u64*    vbits = bits3 + 2*(size_t)MH;
    u64*    fmap3 = (u64*)(r3 + (19u<<20));                // 605 KB
    u64*    fmapp = (u64*)(r3 + (20u<<20));                // 202 KB

    // f32 -> f16 conversions (single batched launch)
    cvt_all<<<NBX + 4*NBW, 256, 0, stream>>>(x, Wq, Wk, Wv, Wp, xh, w3h, wph);

    // QKV projections fused with LIF + bit-pack: grid 99 x (4 col x 3 w)
    gemm_qkv_lif<<<99*12, 256, 0, stream>>>(xh, w3h, bits3, fmap3);
    // exact f64 fixup of flagged chains (corrects single spike bits)
    fixup_qkv<<<2048, 256, 0, stream>>>(x, Wq, Wk, Wv, bits3, fmap3);

    // fused attention: QK^T -> attn_map + PV -> of16 (exact integer math)
    attn_fused<<<dim3(T_*B_, H_, 2), 256, 0, stream>>>(
        qbits, kbits, vbits, attn_out, of16);

    // output projection fused with bias + LIF -> out_spk + flag bitmap
    gemm_proj_lif<<<99*4, 256, 0, stream>>>(of16, wph, bp, out_spk, fmapp);
    fixup_proj<<<1024, 256, 0, stream>>>(of16, Wp, bp, out_spk, fmapp);
}

// Round 15
// 161.237 us; speedup vs baseline: 1.0319x; 1.0319x over previous
//
#include <hip/hip_runtime.h>
#include <stdint.h>

// Problem constants
#define T_ 4
#define B_ 16
#define N_ 197
#define D_ 512
#define H_ 8
#define DH 64
#define BN_ (B_*N_)              // 3152 rows per timestep
#define PLANE (BN_*D_)           // 1,613,824 elems per t-plane
#define M_ (T_*BN_)              // 12608 GEMM rows
#define TENSOR_ELEMS (T_*PLANE)  // 6,455,296 elems per (T,B,N,D) tensor
#define WELEMS (D_*D_)           // 262,144
#define MH (M_*H_)               // 100,864 bitmask words per tensor
#define FLAG_TOL 6e-3f           // ~10 sigma of single-pass f16 dot error
#define NFW3 (3*PLANE/64)        // 75,648 flag words (qkv)
#define NFWP (PLANE/64)          // 25,216 flag words (proj)

typedef __attribute__((ext_vector_type(8))) short short8v;
typedef __attribute__((ext_vector_type(8))) _Float16 f16x8;
typedef __attribute__((ext_vector_type(4))) float f32x4;
typedef __attribute__((ext_vector_type(16))) float f32x16;
typedef __attribute__((ext_vector_type(4))) unsigned short ushort4v;
typedef unsigned long long u64;
typedef unsigned int u32;

__device__ __forceinline__ ushort f16_bits(float f) {
    _Float16 h = (_Float16)f;                      // v_cvt_f16_f32, RNE
    return __builtin_bit_cast(unsigned short, h);
}
__device__ __forceinline__ float f16_val(ushort u) {
    return (float)__builtin_bit_cast(_Float16, u);
}

// async global->LDS 16B copy (one per lane; dest = wave base + lane*16)
__device__ __forceinline__ void gload16(const void* g, void* l) {
    __builtin_amdgcn_global_load_lds(
        (const __attribute__((address_space(1))) unsigned int*)g,
        (__attribute__((address_space(3))) unsigned int*)l, 16, 0, 0);
}

// 8 spike bits -> bf16 0/1 fragment
__device__ __forceinline__ short8v unpack8(u32 bits) {
    short8v r;
    #pragma unroll
    for (int j = 0; j < 8; ++j)
        r[j] = (short)(((bits >> j) & 1u) ? 0x3F80 : 0);
    return r;
}

// ---------------------------------------------------------------------------
// Batched f32 -> f16 convert (x + Wq + Wk + Wv + Wp in one launch)
// ---------------------------------------------------------------------------
#define NBX (TENSOR_ELEMS/1024)  // 6304
#define NBW (WELEMS/1024)        // 256

__global__ void cvt_all(const float* __restrict__ x,  const float* __restrict__ Wq,
                        const float* __restrict__ Wk, const float* __restrict__ Wv,
                        const float* __restrict__ Wp,
                        ushort* __restrict__ xh, ushort* __restrict__ w3h,
                        ushort* __restrict__ wph)
{
    int b = blockIdx.x;
    const float* src; ushort* dst; int base;
    if      (b < NBX)         { src = x;  dst = xh;             base = b; }
    else if (b < NBX + NBW)   { src = Wq; dst = w3h;            base = b - NBX; }
    else if (b < NBX + 2*NBW) { src = Wk; dst = w3h + WELEMS;   base = b - NBX - NBW; }
    else if (b < NBX + 3*NBW) { src = Wv; dst = w3h + 2*WELEMS; base = b - NBX - 2*NBW; }
    else                      { src = Wp; dst = wph;            base = b - NBX - 3*NBW; }
    int i = (base*256 + threadIdx.x)*4;
    float4 v = *(const float4*)(src + i);
    ushort4v o;
    o[0] = f16_bits(v.x); o[1] = f16_bits(v.y);
    o[2] = f16_bits(v.z); o[3] = f16_bits(v.w);
    *(ushort4v*)(dst + i) = o;
}

// ---------------------------------------------------------------------------
// Fused f16 GEMM + LIF + spike-bit pack (QKV). BK=32 double-buffer (32 KB LDS
// -> 4 blocks/CU). Tile: 32 BN-rows x 128 cols x all 4 timesteps.
// (round-12 verified structure)
// ---------------------------------------------------------------------------
__global__ __launch_bounds__(256, 4)
void gemm_qkv_lif(const ushort* __restrict__ xh, const ushort* __restrict__ w3h,
                  u64* __restrict__ bits3, u64* __restrict__ fmap3)
{
    __shared__ __align__(16) ushort smem[16384];   // dbuf x (A 8KB | B 8KB)
    const int tid = threadIdx.x;
    const int lane = tid & 63, wn = tid >> 6;      // wave owns 32 cols
    const int l31 = lane & 31, lg = lane >> 5;
    const int nyz = 12, nz = 3;

    // bijective XCD swizzle + yz-fastest decode
    int nwg = gridDim.x, orig = blockIdx.x;
    int q8 = nwg >> 3, r8 = nwg & 7, xcd = orig & 7, loc = orig >> 3;
    int wg = (xcd < r8 ? xcd*(q8+1) : r8*(q8+1) + (xcd-r8)*q8) + loc;
    int bx = wg / nyz, yz = wg - bx*nyz;
    int by = yz / nz,  z  = yz - by*nz;

    const int bm0 = bx * 32;                       // row offset within BN_
    const int bn0 = by * 128;
    const ushort* Wz = w3h + (size_t)z * WELEMS;

    f32x16 acc[4];
    #pragma unroll
    for (int t = 0; t < 4; ++t)
        #pragma unroll
        for (int r = 0; r < 16; ++r) acc[t][r] = 0.f;

    auto STAGE = [&](int buf, int kt) {
        #pragma unroll
        for (int i = 0; i < 4; ++i) {
            const int q = ((i & 1) << 8) | tid;    // chunk id [0,512)
            const int row = q & 127, c = q >> 7;   // LDS [c][row128][8]
            ushort* dst = smem + buf*8192 + ((i >> 1) << 12) + q*8;
            if (i < 2) {
                int t = row >> 5, r32 = row & 31;
                if (bm0 + r32 < BN_)
                    gload16(xh + ((size_t)(t*BN_ + bm0 + r32)*D_ + kt + c*8), dst);
            } else {
                gload16(Wz + ((size_t)(bn0 + row)*D_ + kt + c*8), dst);
            }
        }
    };
    auto COMPUTE = [&](int buf) {
        const ushort* base = smem + buf*8192;
        #pragma unroll
        for (int s = 0; s < 2; ++s) {
            const int cA = (s << 1) | lg;
            f16x8 bv = *(const f16x8*)&base[4096 + (cA*128 + wn*32 + l31)*8];
            #pragma unroll
            for (int t = 0; t < 4; ++t) {
                f16x8 av = *(const f16x8*)&base[(cA*128 + t*32 + l31)*8];
                acc[t] = __builtin_amdgcn_mfma_f32_32x32x16_f16(av, bv, acc[t], 0, 0, 0);
            }
        }
    };

    STAGE(0, 0);
    __syncthreads();
    int cur = 0;
    #pragma unroll
    for (int k32 = 0; k32 < 16; ++k32) {
        if (k32 < 15) STAGE(cur ^ 1, (k32 + 1)*32);
        COMPUTE(cur);
        __syncthreads();
        cur ^= 1;
    }

    // ---- fused LIF epilogue ----
    // acc[t][r]: row32 = (r&3)+8*(r>>2)+4*lg, col = bn0 + wn*32 + l31
    u32* sp = (u32*)smem;          // [wn][t][r][lg] spike halves (512 u32)
    u32* fl = (u32*)smem + 512;    // [wn][r][lg] flag halves (128 u32)
    #pragma unroll
    for (int r = 0; r < 16; ++r) {
        bool s[4]; bool fg = false; float v = 0.f;
        #pragma unroll
        for (int t = 0; t < 4; ++t) {
            float h = v + (acc[t][r] - v)*0.5f;
            s[t] = h >= 1.0f;
            fg |= fabsf(h - 1.0f) < FLAG_TOL;
            v = s[t] ? 0.f : h;
        }
        #pragma unroll
        for (int t = 0; t < 4; ++t) {
            u64 m = __ballot(s[t]);
            if (lane == 0) {
                sp[((wn*4 + t)*16 + r)*2 + 0] = (u32)m;
                sp[((wn*4 + t)*16 + r)*2 + 1] = (u32)(m >> 32);
            }
        }
        u64 fm = __ballot(fg);
        if (lane == 0) {
            fl[(wn*16 + r)*2 + 0] = (u32)fm;
            fl[(wn*16 + r)*2 + 1] = (u32)(fm >> 32);
        }
    }
    __syncthreads();
    // assemble + store: word(h_local) = low32 from wn=2h, high32 from wn=2h+1
    {
        int t = tid >> 6, row32 = (tid >> 1) & 31, hl = tid & 1;
        int rr = (row32 & 3) | ((row32 >> 3) << 2);
        int lgg = (row32 >> 2) & 1;
        u64 word = (u64)sp[(((2*hl)*4 + t)*16 + rr)*2 + lgg]
                 | ((u64)sp[(((2*hl+1)*4 + t)*16 + rr)*2 + lgg] << 32);
        if (bm0 + row32 < BN_)
            bits3[(size_t)z*MH + (size_t)(t*BN_ + bm0 + row32)*H_ + (bn0 >> 6) + hl] = word;
        if (tid < 64) {
            int rowf = tid >> 1, hlf = tid & 1;
            int rf = (rowf & 3) | ((rowf >> 3) << 2);
            int lgf = (rowf >> 2) & 1;
            u64 fw = (u64)fl[((2*hlf)*16 + rf)*2 + lgf]
                   | ((u64)fl[((2*hlf+1)*16 + rf)*2 + lgf] << 32);
            if (bm0 + rowf < BN_)
                fmap3[(size_t)z*NFWP + (size_t)(bm0 + rowf)*8 + (bn0 >> 6) + hlf] = fw;
        }
    }
}

// ---------------------------------------------------------------------------
// Fused f16 GEMM + bias + LIF (proj). BK=32 double-buffer. (round-12)
// ---------------------------------------------------------------------------
__global__ __launch_bounds__(256, 4)
void gemm_proj_lif(const ushort* __restrict__ oh, const ushort* __restrict__ wph,
                   const float* __restrict__ bias, float* __restrict__ outp,
                   u64* __restrict__ fmapp)
{
    __shared__ __align__(16) ushort smem[16384];
    const int tid = threadIdx.x;
    const int lane = tid & 63, wn = tid >> 6;
    const int l31 = lane & 31, lg = lane >> 5;
    const int nyz = 4;

    int nwg = gridDim.x, orig = blockIdx.x;
    int q8 = nwg >> 3, r8 = nwg & 7, xcd = orig & 7, loc = orig >> 3;
    int wg = (xcd < r8 ? xcd*(q8+1) : r8*(q8+1) + (xcd-r8)*q8) + loc;
    int bx = wg / nyz, by = wg - bx*nyz;

    const int bm0 = bx * 32, bn0 = by * 128;

    f32x16 acc[4];
    #pragma unroll
    for (int t = 0; t < 4; ++t)
        #pragma unroll
        for (int r = 0; r < 16; ++r) acc[t][r] = 0.f;

    auto STAGE = [&](int buf, int kt) {
        #pragma unroll
        for (int i = 0; i < 4; ++i) {
            const int q = ((i & 1) << 8) | tid;
            const int row = q & 127, c = q >> 7;
            ushort* dst = smem + buf*8192 + ((i >> 1) << 12) + q*8;
            if (i < 2) {
                int t = row >> 5, r32 = row & 31;
                if (bm0 + r32 < BN_)
                    gload16(oh + ((size_t)(t*BN_ + bm0 + r32)*D_ + kt + c*8), dst);
            } else {
                gload16(wph + ((size_t)(bn0 + row)*D_ + kt + c*8), dst);
            }
        }
    };
    auto COMPUTE = [&](int buf) {
        const ushort* base = smem + buf*8192;
        #pragma unroll
        for (int s = 0; s < 2; ++s) {
            const int cA = (s << 1) | lg;
            f16x8 bv = *(const f16x8*)&base[4096 + (cA*128 + wn*32 + l31)*8];
            #pragma unroll
            for (int t = 0; t < 4; ++t) {
                f16x8 av = *(const f16x8*)&base[(cA*128 + t*32 + l31)*8];
                acc[t] = __builtin_amdgcn_mfma_f32_32x32x16_f16(av, bv, acc[t], 0, 0, 0);
            }
        }
    };

    STAGE(0, 0);
    __syncthreads();
    int cur = 0;
    #pragma unroll
    for (int k32 = 0; k32 < 16; ++k32) {
        if (k32 < 15) STAGE(cur ^ 1, (k32 + 1)*32);
        COMPUTE(cur);
        __syncthreads();
        cur ^= 1;
    }

    const int gcol = bn0 + wn*32 + l31;
    const float bb = bias[gcol];
    u32* fl = (u32*)smem;          // [wn][r][lg] flag halves
    #pragma unroll
    for (int r = 0; r < 16; ++r) {
        const int row32 = (r & 3) + 8*(r >> 2) + 4*lg;
        const bool live = bm0 + row32 < BN_;
        bool fg = false; float v = 0.f;
        #pragma unroll
        for (int t = 0; t < 4; ++t) {
            float h = v + ((acc[t][r] + bb) - v)*0.5f;
            bool st = h >= 1.0f;
            fg |= fabsf(h - 1.0f) < FLAG_TOL;
            if (live)
                outp[(size_t)t*PLANE + (size_t)(bm0 + row32)*D_ + gcol] = st ? 1.0f : 0.0f;
            v = st ? 0.f : h;
        }
        u64 fm = __ballot(fg);
        if (lane == 0) {
            fl[(wn*16 + r)*2 + 0] = (u32)fm;
            fl[(wn*16 + r)*2 + 1] = (u32)(fm >> 32);
        }
    }
    __syncthreads();
    if (tid < 64) {
        int rowf = tid >> 1, hlf = tid & 1;
        int rf = (rowf & 3) | ((rowf >> 3) << 2);
        int lgf = (rowf >> 2) & 1;
        u64 fw = (u64)fl[((2*hlf)*16 + rf)*2 + lgf]
               | ((u64)fl[((2*hlf+1)*16 + rf)*2 + lgf] << 32);
        if (bm0 + rowf < BN_)
            fmapp[(size_t)(bm0 + rowf)*8 + (bn0 >> 6) + hlf] = fw;
    }
}

// ---------------------------------------------------------------------------
// f64 exact recompute of flagged chains (bitmap scan, 4 waves/block, ILP).
// ---------------------------------------------------------------------------
__global__ __launch_bounds__(256)
void fixup_qkv(const float* __restrict__ x,
               const float* __restrict__ Wq, const float* __restrict__ Wk,
               const float* __restrict__ Wv,
               u64* __restrict__ bits3, const u64* __restrict__ flagmap)
{
    const int lane = threadIdx.x & 63;
    const int wv = blockIdx.x*4 + (threadIdx.x >> 6);
    const int nw = gridDim.x*4;
    for (int w = wv; w < NFW3; w += nw) {
        u64 fm = flagmap[w];
        while (fm) {
            int bit = __ffsll((long long)fm) - 1;
            fm &= fm - 1;
            int id = (w << 6) + bit;
            int tsr = id / PLANE;
            int rem = id - tsr*PLANE;
            int r = rem >> 9, e = rem & (D_-1);
            const float* W = (tsr==0) ? Wq : (tsr==1 ? Wk : Wv);
            const float* wr = W + (size_t)e*D_;
            u64* bits = bits3 + (size_t)tsr*MH;
            float wv8[8];
            #pragma unroll
            for (int i = 0; i < 8; ++i) wv8[i] = wr[lane + 64*i];
            double dots[T_];
            #pragma unroll
            for (int t = 0; t < T_; ++t) {
                const float* xr = x + (size_t)(t*BN_ + r)*D_;
                float xv8[8];
                #pragma unroll
                for (int i = 0; i < 8; ++i) xv8[i] = xr[lane + 64*i];
                double p = 0.0;
                #pragma unroll
                for (int i = 0; i < 8; ++i) p += (double)xv8[i]*(double)wv8[i];
                dots[t] = p;
            }
            #pragma unroll
            for (int off = 32; off > 0; off >>= 1)
                #pragma unroll
                for (int t = 0; t < T_; ++t)
                    dots[t] += __shfl_down(dots[t], off);
            if (lane == 0) {
                double v = 0.0;
                u64 b = 1ull << (e & 63);
                #pragma unroll
                for (int t = 0; t < T_; ++t) {
                    double hh = v + (dots[t] - v)/2.0;
                    bool s = hh >= 1.0;
                    size_t wd = (size_t)(t*BN_ + r)*H_ + (e >> 6);
                    if (s) atomicOr(&bits[wd], b);
                    else   atomicAnd(&bits[wd], ~b);
                    v = s ? 0.0 : hh;
                }
            }
        }
    }
}

// ---------------------------------------------------------------------------
// Fused MFMA attention (round-12 structure, no z-split) + T5 setprio around
// MFMA clusters (waves are phase-independent -> scheduler can favor MFMA).
// ---------------------------------------------------------------------------
#define JP 224   // 7 * 32 (padded j for PV K-dim)
#define VSTR 232 // LDS row stride for Vt / Ss

__global__ __launch_bounds__(256)
void attn_fused(const u64* __restrict__ qbits, const u64* __restrict__ kbits,
                const u64* __restrict__ vbits,
                float* __restrict__ attn_out, ushort* __restrict__ of16)
{
    __shared__ ushort Vt[DH][VSTR];
    __shared__ ushort Ss[4][16][VSTR];
    int tb = blockIdx.x, h = blockIdx.y;
    int tid = threadIdx.x, wave = tid >> 6, lane = tid & 63;

    // stage V transposed from vbits: Vt[d][j], j >= N_ zeroed
    for (int idx = tid; idx < JP*16; idx += 256) {
        int j = idx >> 4, d4 = (idx & 15) << 2;
        ushort vv[4] = {0,0,0,0};
        if (j < N_) {
            u64 vw = vbits[((size_t)tb*N_ + j)*H_ + h];
            #pragma unroll
            for (int r = 0; r < 4; ++r)
                vv[r] = ((vw >> (d4+r)) & 1ull) ? 0x3F80 : 0;
        }
        Vt[d4+0][j]=vv[0]; Vt[d4+1][j]=vv[1]; Vt[d4+2][j]=vv[2]; Vt[d4+3][j]=vv[3];
    }
    // zero Ss pad cols [208, 224)
    for (int idx = lane; idx < 16*16; idx += 64)
        Ss[wave][idx >> 4][208 + (idx & 15)] = 0;
    __syncthreads();

    const int il = lane & 15, kk = (lane >> 4) << 3, ig = (lane >> 4) << 2;
    const size_t amap = ((size_t)tb*H_ + h)*(size_t)(N_*N_);

    for (int it = wave; it < 13; it += 4) {
        int i0 = it << 4;
        // A-fragments straight from qbits
        int qrow = i0 + il;
        u64 qw = (qrow < N_) ? qbits[((size_t)tb*N_ + qrow)*H_ + h] : 0ull;
        short8v a0 = unpack8((u32)(qw >> kk));
        short8v a1 = unpack8((u32)((qw >> 32) >> kk));
        // QK^T over 13 col-tiles -> bf16 S strip (exact)
        for (int jt = 0; jt < 13; ++jt) {
            int j0 = jt << 4, jrow = j0 + il;
            u64 kw = (jrow < N_) ? kbits[((size_t)tb*N_ + jrow)*H_ + h] : 0ull;
            short8v b0 = unpack8((u32)(kw >> kk));
            short8v b1 = unpack8((u32)((kw >> 32) >> kk));
            f32x4 c = {0.f, 0.f, 0.f, 0.f};
            __builtin_amdgcn_s_setprio(1);
            c = __builtin_amdgcn_mfma_f32_16x16x32_bf16(a0, b0, c, 0, 0, 0);
            c = __builtin_amdgcn_mfma_f32_16x16x32_bf16(a1, b1, c, 0, 0, 0);
            __builtin_amdgcn_s_setprio(0);
            int j = j0 + il;               // C col = lane&15
            #pragma unroll
            for (int r = 0; r < 4; ++r) {
                float sv = c[r]*0.125f;    // exact: k/8, k <= 64
                Ss[wave][ig + r][j] = (ushort)(__float_as_uint(sv) >> 16);
            }
        }
        // coalesced attn_map row stores (bf16 -> f32 shift, exact)
        #pragma unroll
        for (int r = 0; r < 16; ++r) {
            int i = i0 + r;
            if (i < N_) {
                #pragma unroll
                for (int g = 0; g < 4; ++g) {
                    int col = g*64 + lane;
                    if (col < N_)
                        attn_out[amap + (size_t)i*N_ + col] =
                            __uint_as_float((u32)Ss[wave][r][col] << 16);
                }
            }
        }
        // PV for this strip
        f32x4 o[4];
        #pragma unroll
        for (int dt = 0; dt < 4; ++dt) o[dt] = (f32x4){0.f,0.f,0.f,0.f};
        __builtin_amdgcn_s_setprio(1);
        #pragma unroll
        for (int kt = 0; kt < 7; ++kt) {
            short8v a = *(const short8v*)&Ss[wave][il][kt*32 + kk];
            #pragma unroll
            for (int dt = 0; dt < 4; ++dt) {
                short8v b = *(const short8v*)&Vt[dt*16 + il][kt*32 + kk];
                o[dt] = __builtin_amdgcn_mfma_f32_16x16x32_bf16(a, b, o[dt], 0, 0, 0);
            }
        }
        __builtin_amdgcn_s_setprio(0);
        #pragma unroll
        for (int dt = 0; dt < 4; ++dt)
            #pragma unroll
            for (int r = 0; r < 4; ++r) {
                int i = i0 + ig + r;
                if (i < N_)
                    of16[((size_t)tb*N_ + i)*D_ + (size_t)h*DH + dt*16 + il] =
                        f16_bits(o[dt][r]);
            }
    }
}

// ---------------------------------------------------------------------------
// fixup_proj: exact f64 recompute of flagged proj chains (reads of16, exact).
// ---------------------------------------------------------------------------
__global__ __launch_bounds__(256)
void fixup_proj(const ushort* __restrict__ of16, const float* __restrict__ Wp,
                const float* __restrict__ bp, float* __restrict__ outp,
                const u64* __restrict__ flagmap)
{
    const int lane = threadIdx.x & 63;
    const int wv = blockIdx.x*4 + (threadIdx.x >> 6);
    const int nw = gridDim.x*4;
    for (int w = wv; w < NFWP; w += nw) {
        u64 fm = flagmap[w];
        while (fm) {
            int bit = __ffsll((long long)fm) - 1;
            fm &= fm - 1;
            int rem = (w << 6) + bit;
            int r = rem >> 9, e = rem & (D_-1);
            const float* wr = Wp + (size_t)e*D_;
            float wv8[8];
            #pragma unroll
            for (int i = 0; i < 8; ++i) wv8[i] = wr[lane + 64*i];
            double dots[T_];
            #pragma unroll
            for (int t = 0; t < T_; ++t) {
                const ushort* ar = of16 + (size_t)(t*BN_ + r)*D_;
                float av8[8];
                #pragma unroll
                for (int i = 0; i < 8; ++i) av8[i] = f16_val(ar[lane + 64*i]);
                double p = 0.0;
                #pragma unroll
                for (int i = 0; i < 8; ++i) p += (double)av8[i]*(double)wv8[i];
                dots[t] = p;
            }
            #pragma unroll
            for (int off = 32; off > 0; off >>= 1)
                #pragma unroll
                for (int t = 0; t < T_; ++t)
                    dots[t] += __shfl_down(dots[t], off);
            if (lane == 0) {
                double v = 0.0;
                #pragma unroll
                for (int t = 0; t < T_; ++t) {
                    double xt = dots[t] + (double)bp[e];
                    double h = v + (xt - v)/2.0;
                    bool s = h >= 1.0;
                    outp[(size_t)t*PLANE + rem] = s ? 1.0f : 0.0f;
                    v = s ? 0.0 : h;
                }
            }
        }
    }
}

// ---------------------------------------------------------------------------
extern "C" void kernel_launch(void* const* d_in, const int* in_sizes, int n_in,
                              void* d_out, int out_size, void* d_ws, size_t ws_size,
                              hipStream_t stream)
{
    const float* x  = (const float*)d_in[0];
    const float* Wq = (const float*)d_in[1];
    const float* Wk = (const float*)d_in[2];
    const float* Wv = (const float*)d_in[3];
    const float* Wp = (const float*)d_in[4];
    const float* bp = (const float*)d_in[5];
    float* out_spk  = (float*)d_out;                       // (T,B,N,D) spikes
    float* attn_out = (float*)d_out + TENSOR_ELEMS;        // (T,B,H,N,N)

    char* ws = (char*)d_ws;
    const size_t BUFB = (size_t)TENSOR_ELEMS * sizeof(float);   // 25.8 MB
    if (ws_size < 4*BUFB) return;
    // R2: O f16 (proj GEMM + fixup operand; exact)
    ushort* of16 = (ushort*)(ws + 2*BUFB);
    // R3: xh f16 | w3h | wph | bits | flag bitmaps
    char* r3 = ws + 3*BUFB;
    ushort* xh   = (ushort*)r3;                            // 12.9 MB
    ushort* w3h  = (ushort*)(r3 + (13u<<20));              // 1.5 MB
    ushort* wph  = (ushort*)(r3 + (15u<<20));              // 0.5 MB
    u64*    bits3 = (u64*)(r3 + (16u<<20));                // 2.42 MB
    u64*    qbits = bits3;
    u64*    kbits = bits3 + MH;
    u64*    vbits = bits3 + 2*(size_t)MH;
    u64*    fmap3 = (u64*)(r3 + (19u<<20));                // 605 KB
    u64*    fmapp = (u64*)(r3 + (20u<<20));                // 202 KB

    // f32 -> f16 conversions (single batched launch)
    cvt_all<<<NBX + 4*NBW, 256, 0, stream>>>(x, Wq, Wk, Wv, Wp, xh, w3h, wph);

    // QKV projections fused with LIF + bit-pack: grid 99 x (4 col x 3 w)
    gemm_qkv_lif<<<99*12, 256, 0, stream>>>(xh, w3h, bits3, fmap3);
    // exact f64 fixup of flagged chains (corrects single spike bits)
    fixup_qkv<<<2048, 256, 0, stream>>>(x, Wq, Wk, Wv, bits3, fmap3);

    // fused attention: QK^T -> attn_map + PV -> of16 (exact integer math)
    attn_fused<<<dim3(T_*B_, H_), 256, 0, stream>>>(
        qbits, kbits, vbits, attn_out, of16);

    // output projection fused with bias + LIF -> out_spk + flag bitmap
    gemm_proj_lif<<<99*4, 256, 0, stream>>>(of16, wph, bp, out_spk, fmapp);
    fixup_proj<<<1024, 256, 0, stream>>>(of16, Wp, bp, out_spk, fmapp);
}